// Round 3
// baseline (779.012 us; speedup 1.0000x reference)
//
#include <hip/hip_runtime.h>
#include <stdint.h>

// Problem constants (fixed by the reference)
#define DIM     256
#define NCODES  4096
#define NROWS   65536         // 64*32*32
#define ROWS_WG 128
#define CCOLS   64            // codes per chunk in k2
#define NCH     (NCODES / CCOLS)   // 64

// Workspace layout (bytes). Total ~2.33 MB.
#define OFF_BIMG  0u                       // bf16 codebook image: 4096*256*2 = 2 MiB
#define OFF_HC    (1u << 21)               // 4096 floats: 0.125 + 0.5*||e||^2
#define OFF_IDX   ((1u << 21) + 16384u)    // 65536 int best-code indices
#define OFF_PART  (OFF_IDX + 262144u)      // 16384 float per-block loss partials

typedef __attribute__((ext_vector_type(8)))  __bf16 bf16x8;
typedef __attribute__((ext_vector_type(16))) float  f32x16;

// fp32 -> bf16 round-to-nearest-even, as a uint16 in the low bits
__device__ __forceinline__ uint32_t f2bf(float f) {
  uint32_t u = __float_as_uint(f);
  return (u + 0x7FFFu + ((u >> 16) & 1u)) >> 16;
}

// ---------------------------------------------------------------------------
// k1: codebook -> bf16 image in MFMA-B layout + hc[] = 0.125 + 0.5*||e||^2
// Image layout per 64-code chunk (32 KiB): byte off = kb*1024 + col*16,
// kb = k/8 (16B of 8 bf16), col = code within chunk. A wave's B-fragment
// (32 consecutive cols x 16B, both k-groups) is 64 lanes x 16B contiguous ->
// one coalesced global_load_dwordx4 straight into VGPRs (no LDS needed).
// ---------------------------------------------------------------------------
__global__ __launch_bounds__(64) void k1_prep(const float* __restrict__ cb,
                                              uint8_t* __restrict__ ws) {
  const int code = blockIdx.x;      // 0..4095
  const int l = threadIdx.x;        // 0..63, handles k = 4l..4l+3
  float4 v = ((const float4*)(cb + (size_t)code * DIM))[l];
  uint32_t lo = f2bf(v.x) | (f2bf(v.y) << 16);
  uint32_t hi = f2bf(v.z) | (f2bf(v.w) << 16);
  uint32_t off = (uint32_t)(code >> 6) * 32768u + (uint32_t)(l >> 1) * 1024u
               + (uint32_t)(code & 63) * 16u + (uint32_t)(l & 1) * 8u;
  uint32_t* dst = (uint32_t*)(ws + OFF_BIMG + off);
  dst[0] = lo;
  dst[1] = hi;
  float s = v.x * v.x + v.y * v.y + v.z * v.z + v.w * v.w;
  #pragma unroll
  for (int m = 1; m < 64; m <<= 1) s += __shfl_xor(s, m, 64);
  if (l == 0) ((float*)(ws + OFF_HC))[code] = 0.125f + 0.5f * s;
}

// ---------------------------------------------------------------------------
// k2: fused bf16-MFMA GEMM + argmin. One WG = 128 rows, loops all 4096 codes.
// A fragments in registers (AGPR-eligible, 128 regs). B fragments direct
// global->VGPR with EXPLICIT register double-buffering (b0/b1, 128 VGPRs):
// chunk ch+1's 16 loads are issued before chunk ch's MFMAs, so L2 latency
// (~300-600 cyc) hides under ~2048 cyc of per-SIMD MFMA work. Barrier-free
// main loop; round-2's per-chunk exposed-latency serialization removed.
// score = (0.125 + 0.5||e||^2) - x.e  (row-constant ||x||^2 dropped; always
// positive -> fp32 bits order-isomorphic as u32). 12-bit code index embedded
// in low mantissa bits; running argmin = v_and_or + v_min_u32.
// ---------------------------------------------------------------------------
__global__ __launch_bounds__(256, 2) void k2_argmin(const float* __restrict__ x,
                                                    uint8_t* __restrict__ ws) {
  __shared__ uint4 smem4[2048];     // 32 KiB
  const int t = threadIdx.x;
  const int wave = t >> 6;
  const int lane = t & 63;
  const int c = lane & 31;          // MFMA row/col lane index
  const int g = lane >> 5;          // MFMA k-group
  const int wg = blockIdx.x;
  const uint8_t* __restrict__ Bimg = ws + OFF_BIMG;
  const float* __restrict__ hcg = (const float*)(ws + OFF_HC);
  int* bidx = (int*)(ws + OFF_IDX);

  // wave grid: 2x2 over (128 rows x 64 cols); wave tile = 64 rows x 32 cols
  const int rbw = (wave >> 1) * 64;   // wave row base
  const int cbw = (wave & 1) * 32;    // wave col base within chunk

  // ---- stage A (128 rows x 256) in two 32 KiB half-passes; frags -> regs ----
  bf16x8 a[2][16];
  {
    const float* xb = x + (size_t)wg * ROWS_WG * DIM;
    #pragma unroll
    for (int p = 0; p < 2; ++p) {
      #pragma unroll
      for (int it = 0; it < 8; ++it) {
        int f = it * 256 + t;
        int row = f & 63;
        int kb = f >> 6;              // 0..31
        const float4* src = (const float4*)(xb + (size_t)(p * 64 + row) * DIM + kb * 8);
        float4 v0 = src[0], v1 = src[1];
        uint4 q;
        q.x = f2bf(v0.x) | (f2bf(v0.y) << 16);
        q.y = f2bf(v0.z) | (f2bf(v0.w) << 16);
        q.z = f2bf(v1.x) | (f2bf(v1.y) << 16);
        q.w = f2bf(v1.z) | (f2bf(v1.w) << 16);
        smem4[kb * 64 + row] = q;     // consecutive 16B per lane: conflict-free
      }
      __syncthreads();
      if ((wave >> 1) == p) {
        #pragma unroll
        for (int rt = 0; rt < 2; ++rt)
          #pragma unroll
          for (int ks = 0; ks < 16; ++ks)
            a[rt][ks] = *(const bf16x8*)&smem4[(ks * 2 + g) * 64 + rt * 32 + c];
      }
      __syncthreads();
    }
  }

  // ---- main loop: 64 chunks of 64 codes, barrier-free, SW-pipelined ----
  uint32_t key[2][16];
  #pragma unroll
  for (int rt = 0; rt < 2; ++rt)
    #pragma unroll
    for (int r = 0; r < 16; ++r) key[rt][r] = 0xFFFFFFFFu;

  const uint8_t* bbase = Bimg + (size_t)(cbw + c) * 16 + (size_t)g * 1024;
  const int hoff = cbw + c;
  const uint32_t maskhi = 0xFFFFF000u;            // keep 20 high bits of score

  bf16x8 b0[16], b1[16];
  float h0, h1;

  // prime chunk 0
  #pragma unroll
  for (int ks = 0; ks < 16; ++ks)
    b0[ks] = *(const bf16x8*)(bbase + ks * 2048);
  h0 = hcg[hoff];

  auto compute = [&](const bf16x8* bb, float h, uint32_t col) {
    f32x16 acc0 = (f32x16)0.0f;
    f32x16 acc1 = (f32x16)0.0f;
    #pragma unroll
    for (int ks = 0; ks < 16; ++ks) {
      acc0 = __builtin_amdgcn_mfma_f32_32x32x16_bf16(a[0][ks], bb[ks], acc0, 0, 0, 0);
      acc1 = __builtin_amdgcn_mfma_f32_32x32x16_bf16(a[1][ks], bb[ks], acc1, 0, 0, 0);
    }
    #pragma unroll
    for (int r = 0; r < 16; ++r) {
      uint32_t k0 = (__float_as_uint(h - acc0[r]) & maskhi) | col;
      uint32_t k1 = (__float_as_uint(h - acc1[r]) & maskhi) | col;
      if (k0 < key[0][r]) key[0][r] = k0;         // v_min_u32
      if (k1 < key[1][r]) key[1][r] = k1;
    }
  };

  for (int ch = 0; ch < NCH; ch += 2) {
    // prefetch ch+1 (always exists: NCH even, ch <= 62)
    {
      const uint8_t* bp = bbase + (size_t)(ch + 1) * 32768;
      #pragma unroll
      for (int ks = 0; ks < 16; ++ks)
        b1[ks] = *(const bf16x8*)(bp + ks * 2048);
      h1 = hcg[(ch + 1) * CCOLS + hoff];
    }
    compute(b0, h0, (uint32_t)(ch * CCOLS + hoff));

    // prefetch ch+2
    if (ch + 2 < NCH) {
      const uint8_t* bp = bbase + (size_t)(ch + 2) * 32768;
      #pragma unroll
      for (int ks = 0; ks < 16; ++ks)
        b0[ks] = *(const bf16x8*)(bp + ks * 2048);
      h0 = hcg[(ch + 2) * CCOLS + hoff];
    }
    compute(b1, h1, (uint32_t)((ch + 1) * CCOLS + hoff));
  }

  // ---- cross-lane argmin over the 32 col-lanes (within each 32-lane half) ----
  #pragma unroll
  for (int rt = 0; rt < 2; ++rt)
    #pragma unroll
    for (int r = 0; r < 16; ++r) {
      uint32_t k = key[rt][r];
      #pragma unroll
      for (int m = 1; m < 32; m <<= 1) {
        uint32_t ko = (uint32_t)__shfl_xor((int)k, m, 32);
        if (ko < k) k = ko;
      }
      key[rt][r] = k;
    }

  // ---- combine the two col-waves per row via LDS u32 atomicMin ----
  uint32_t* bk = (uint32_t*)&smem4[0];
  if (t < 128) bk[t] = 0xFFFFFFFFu;
  __syncthreads();
  if (c == 0) {
    #pragma unroll
    for (int rt = 0; rt < 2; ++rt)
      #pragma unroll
      for (int r = 0; r < 16; ++r) {
        int rl = rbw + rt * 32 + (r & 3) + ((r >> 2) << 3) + (g << 2);
        atomicMin(&bk[rl], key[rt][r]);
      }
  }
  __syncthreads();
  if (t < 128) bidx[wg * ROWS_WG + t] = (int)(bk[t] & 0xFFFu);
}

// ---------------------------------------------------------------------------
// k3: gather fp32 codebook rows -> out0 (== straight-through value to ulp),
// and exact fp32 per-block partial sums of (q - x)^2.
// ---------------------------------------------------------------------------
__global__ __launch_bounds__(256) void k3_finalize(const float* __restrict__ x,
                                                   const float* __restrict__ cb,
                                                   uint8_t* __restrict__ ws,
                                                   float* __restrict__ out) {
  const int t = threadIdx.x;
  const size_t i4 = (size_t)blockIdx.x * 256 + t;   // float4 index
  const int row = (int)(i4 >> 6);
  const int k4 = (int)(i4 & 63);
  const int* bidx = (const int*)(ws + OFF_IDX);
  const int code = bidx[row] & (NCODES - 1);
  float4 q = ((const float4*)(cb + (size_t)code * DIM))[k4];
  float4 xv = ((const float4*)x)[i4];
  ((float4*)out)[i4] = q;
  float dx = q.x - xv.x, dy = q.y - xv.y, dz = q.z - xv.z, dw = q.w - xv.w;
  float p = dx * dx + dy * dy + dz * dz + dw * dw;
  #pragma unroll
  for (int m = 1; m < 64; m <<= 1) p += __shfl_xor(p, m, 64);
  __shared__ float ps[4];
  if ((t & 63) == 0) ps[t >> 6] = p;
  __syncthreads();
  if (t == 0)
    ((float*)(ws + OFF_PART))[blockIdx.x] = ps[0] + ps[1] + ps[2] + ps[3];
}

// ---------------------------------------------------------------------------
// k4: reduce 16384 partials -> vq_loss = 1.25 * mean((q-x)^2)
// (codebook_loss + 0.25*commitment_loss; both equal numerically)
// ---------------------------------------------------------------------------
__global__ __launch_bounds__(256) void k4_loss(const uint8_t* __restrict__ ws,
                                               float* __restrict__ out,
                                               int out_size) {
  const float* part = (const float*)(ws + OFF_PART);
  float s = 0.0f;
  for (int i = threadIdx.x; i < 16384; i += 256) s += part[i];
  #pragma unroll
  for (int m = 1; m < 64; m <<= 1) s += __shfl_xor(s, m, 64);
  __shared__ float ps[4];
  if ((threadIdx.x & 63) == 0) ps[threadIdx.x >> 6] = s;
  __syncthreads();
  if (threadIdx.x == 0)
    out[out_size - 1] =
        1.25f * (ps[0] + ps[1] + ps[2] + ps[3]) * (1.0f / 16777216.0f);
}

extern "C" void kernel_launch(void* const* d_in, const int* in_sizes, int n_in,
                              void* d_out, int out_size, void* d_ws, size_t ws_size,
                              hipStream_t stream) {
  const float* x = (const float*)d_in[0];        // [65536, 256] fp32
  const float* cb = (const float*)d_in[1];       // [4096, 256] fp32
  uint8_t* ws = (uint8_t*)d_ws;
  float* out = (float*)d_out;                    // 16777216 floats + 1 loss

  k1_prep<<<dim3(NCODES), dim3(64), 0, stream>>>(cb, ws);
  k2_argmin<<<dim3(NROWS / ROWS_WG), dim3(256), 0, stream>>>(x, ws);
  k3_finalize<<<dim3(16384), dim3(256), 0, stream>>>(x, cb, ws, out);
  k4_loss<<<dim3(1), dim3(256), 0, stream>>>(ws, out, out_size);
}

// Round 4
// 272.784 us; speedup vs baseline: 2.8558x; 2.8558x over previous
//
#include <hip/hip_runtime.h>
#include <stdint.h>

// Problem constants (fixed by the reference)
#define DIM     256
#define NCODES  4096
#define NROWS   65536         // 64*32*32
#define ROWS_WG 128
#define CCOLS   64            // codes per chunk in k2
#define NCH     (NCODES / CCOLS)   // 64

// Workspace layout (bytes). Total ~2.33 MB.
#define OFF_BIMG  0u                       // bf16 codebook image: 4096*256*2 = 2 MiB
#define OFF_HC    (1u << 21)               // 4096 floats: 0.125 + 0.5*||e||^2
#define OFF_IDX   ((1u << 21) + 16384u)    // 65536 int best-code indices
#define OFF_PART  (OFF_IDX + 262144u)      // 16384 float per-block loss partials

typedef __attribute__((ext_vector_type(8)))  __bf16 bf16x8;
typedef __attribute__((ext_vector_type(16))) float  f32x16;
typedef const __attribute__((address_space(1))) uint32_t* gas1_t;
typedef __attribute__((address_space(3))) uint32_t*       las3_t;

// fp32 -> bf16 round-to-nearest-even, as a uint16 in the low bits
__device__ __forceinline__ uint32_t f2bf(float f) {
  uint32_t u = __float_as_uint(f);
  return (u + 0x7FFFu + ((u >> 16) & 1u)) >> 16;
}

// ---------------------------------------------------------------------------
// k1: codebook -> bf16 image in MFMA-B layout + hc[] = 0.125 + 0.5*||e||^2
// Image layout per 64-code chunk (32 KiB): byte off = kb*1024 + col*16,
// kb = k/8 (16B of 8 bf16), col = code within chunk. k2's global_load_lds
// staging of a chunk is then a pure linear copy, and B-fragment ds_read_b128
// (32 consecutive cols) is bank-conflict-free.
// ---------------------------------------------------------------------------
__global__ __launch_bounds__(64) void k1_prep(const float* __restrict__ cb,
                                              uint8_t* __restrict__ ws) {
  const int code = blockIdx.x;      // 0..4095
  const int l = threadIdx.x;        // 0..63, handles k = 4l..4l+3
  float4 v = ((const float4*)(cb + (size_t)code * DIM))[l];
  uint32_t lo = f2bf(v.x) | (f2bf(v.y) << 16);
  uint32_t hi = f2bf(v.z) | (f2bf(v.w) << 16);
  uint32_t off = (uint32_t)(code >> 6) * 32768u + (uint32_t)(l >> 1) * 1024u
               + (uint32_t)(code & 63) * 16u + (uint32_t)(l & 1) * 8u;
  uint32_t* dst = (uint32_t*)(ws + OFF_BIMG + off);
  dst[0] = lo;
  dst[1] = hi;
  float s = v.x * v.x + v.y * v.y + v.z * v.z + v.w * v.w;
  #pragma unroll
  for (int m = 1; m < 64; m <<= 1) s += __shfl_xor(s, m, 64);
  if (l == 0) ((float*)(ws + OFF_HC))[code] = 0.125f + 0.5f * s;
}

// ---------------------------------------------------------------------------
// k2: fused bf16-MFMA GEMM + argmin. One WG = 128 rows, loops all 4096 codes.
// Round-1 structure (A in regs, B double-buffered in LDS via global_load_lds
// DMA — each chunk read from L2 exactly ONCE per WG, no VGPR data regs) with
// round-2's compressed argmin keys. Register total ~217 < 256 -> 2 blocks/CU:
// the per-chunk barrier drain (round 1's killer at 1 block/CU) is covered by
// the co-resident block's waves, and nothing spills (round 3's killer).
// score = (0.125 + 0.5||e||^2) - x.e  (row-constant ||x||^2 dropped; always
// positive -> fp32 bits order-isomorphic as u32). 12-bit code index embedded
// in low mantissa bits; running argmin = v_and_or + v_min_u32.
// ---------------------------------------------------------------------------
__global__ __launch_bounds__(256, 2) void k2_argmin(const float* __restrict__ x,
                                                    uint8_t* __restrict__ ws) {
  __shared__ uint4 smem4[4096];     // exactly 64 KiB; x2 blocks = 128 <= 160
  char* smem = (char*)&smem4[0];
  const int t = threadIdx.x;
  const int wave = t >> 6;
  const int lane = t & 63;
  const int c = lane & 31;          // MFMA row/col lane index
  const int g = lane >> 5;          // MFMA k-group
  const int wg = blockIdx.x;
  const uint8_t* __restrict__ Bimg = ws + OFF_BIMG;
  const float* __restrict__ hcg = (const float*)(ws + OFF_HC);
  int* bidx = (int*)(ws + OFF_IDX);

  // wave grid: 2x2 over (128 rows x 64 cols); wave tile = 64 rows x 32 cols
  const int rbw = (wave >> 1) * 64;   // wave row base
  const int cbw = (wave & 1) * 32;    // wave col base within chunk

  // ---- stage A tile (128 rows x 256) as bf16 image across full 64 KiB ----
  // image: byte off = kb*2048 + row*16  (kb = k/8)
  {
    const float* xb = x + (size_t)wg * ROWS_WG * DIM;
    #pragma unroll
    for (int it = 0; it < 16; ++it) {
      int f = it * 256 + t;
      int row = f & 127;
      int kb = f >> 7;              // 0..31
      const float4* src = (const float4*)(xb + (size_t)row * DIM + kb * 8);
      float4 v0 = src[0], v1 = src[1];
      uint4 q;
      q.x = f2bf(v0.x) | (f2bf(v0.y) << 16);
      q.y = f2bf(v0.z) | (f2bf(v0.w) << 16);
      q.z = f2bf(v1.x) | (f2bf(v1.y) << 16);
      q.w = f2bf(v1.z) | (f2bf(v1.w) << 16);
      smem4[kb * 128 + row] = q;    // lanes hit consecutive 16B: conflict-free
    }
  }
  __syncthreads();

  // ---- A fragments to registers (mfma_32x32x16 A layout) ----
  bf16x8 a[2][16];
  #pragma unroll
  for (int rt = 0; rt < 2; ++rt)
    #pragma unroll
    for (int ks = 0; ks < 16; ++ks)
      a[rt][ks] = *(const bf16x8*)&smem4[(ks * 2 + g) * 128 + rbw + rt * 32 + c];
  __syncthreads();   // lgkm drained before barrier -> a[] safe; LDS reusable

  auto stageB = [&](int buf, int ch) {
    const uint8_t* gsrc = Bimg + (size_t)ch * 32768 + (size_t)t * 16;
    char* lb = smem + buf * 32768 + (t & 192) * 16;   // wave-uniform base
    #pragma unroll
    for (int i = 0; i < 8; ++i)
      __builtin_amdgcn_global_load_lds((gas1_t)(uintptr_t)(gsrc + i * 4096),
                                       (las3_t)(uintptr_t)(lb + i * 4096),
                                       16, 0, 0);
  };

  uint32_t key[2][16];
  #pragma unroll
  for (int rt = 0; rt < 2; ++rt)
    #pragma unroll
    for (int r = 0; r < 16; ++r) key[rt][r] = 0xFFFFFFFFu;

  const int hoff = cbw + c;
  const uint32_t maskhi = 0xFFFFF000u;     // keep 20 high bits of score

  stageB(0, 0);

  for (int ch = 0; ch < NCH; ++ch) {
    const int cur = ch & 1;
    __syncthreads();   // implied vmcnt(0): chunk ch landed; prev buf free
    if (ch + 1 < NCH) stageB(cur ^ 1, ch + 1);   // async, overlaps compute

    float h = hcg[ch * CCOLS + hoff];            // L2-hot, consumed late
    f32x16 acc0 = (f32x16)0.0f;
    f32x16 acc1 = (f32x16)0.0f;
    const int bb = cur * 2048;                   // buffer base in uint4 units
    #pragma unroll
    for (int ks = 0; ks < 16; ++ks) {
      bf16x8 b = *(const bf16x8*)&smem4[bb + (ks * 2 + g) * 64 + cbw + c];
      acc0 = __builtin_amdgcn_mfma_f32_32x32x16_bf16(a[0][ks], b, acc0, 0, 0, 0);
      acc1 = __builtin_amdgcn_mfma_f32_32x32x16_bf16(a[1][ks], b, acc1, 0, 0, 0);
    }
    const uint32_t col = (uint32_t)(ch * CCOLS + hoff);
    #pragma unroll
    for (int r = 0; r < 16; ++r) {
      uint32_t k0 = (__float_as_uint(h - acc0[r]) & maskhi) | col;
      uint32_t k1 = (__float_as_uint(h - acc1[r]) & maskhi) | col;
      if (k0 < key[0][r]) key[0][r] = k0;        // v_min_u32
      if (k1 < key[1][r]) key[1][r] = k1;
    }
  }

  // ---- cross-lane argmin over the 32 col-lanes (within each 32-lane half) ----
  #pragma unroll
  for (int rt = 0; rt < 2; ++rt)
    #pragma unroll
    for (int r = 0; r < 16; ++r) {
      uint32_t k = key[rt][r];
      #pragma unroll
      for (int m = 1; m < 32; m <<= 1) {
        uint32_t ko = (uint32_t)__shfl_xor((int)k, m, 32);
        if (ko < k) k = ko;
      }
      key[rt][r] = k;
    }

  // ---- combine the two col-waves per row via LDS u32 atomicMin ----
  uint32_t* bk = (uint32_t*)smem;
  __syncthreads();                  // main-loop LDS reads done before reuse
  if (t < 128) bk[t] = 0xFFFFFFFFu;
  __syncthreads();
  if (c == 0) {
    #pragma unroll
    for (int rt = 0; rt < 2; ++rt)
      #pragma unroll
      for (int r = 0; r < 16; ++r) {
        int rl = rbw + rt * 32 + (r & 3) + ((r >> 2) << 3) + (g << 2);
        atomicMin(&bk[rl], key[rt][r]);
      }
  }
  __syncthreads();
  if (t < 128) bidx[wg * ROWS_WG + t] = (int)(bk[t] & 0xFFFu);
}

// ---------------------------------------------------------------------------
// k3: gather fp32 codebook rows -> out0 (== straight-through value to ulp),
// and exact fp32 per-block partial sums of (q - x)^2.
// ---------------------------------------------------------------------------
__global__ __launch_bounds__(256) void k3_finalize(const float* __restrict__ x,
                                                   const float* __restrict__ cb,
                                                   uint8_t* __restrict__ ws,
                                                   float* __restrict__ out) {
  const int t = threadIdx.x;
  const size_t i4 = (size_t)blockIdx.x * 256 + t;   // float4 index
  const int row = (int)(i4 >> 6);
  const int k4 = (int)(i4 & 63);
  const int* bidx = (const int*)(ws + OFF_IDX);
  const int code = bidx[row] & (NCODES - 1);
  float4 q = ((const float4*)(cb + (size_t)code * DIM))[k4];
  float4 xv = ((const float4*)x)[i4];
  ((float4*)out)[i4] = q;
  float dx = q.x - xv.x, dy = q.y - xv.y, dz = q.z - xv.z, dw = q.w - xv.w;
  float p = dx * dx + dy * dy + dz * dz + dw * dw;
  #pragma unroll
  for (int m = 1; m < 64; m <<= 1) p += __shfl_xor(p, m, 64);
  __shared__ float ps[4];
  if ((t & 63) == 0) ps[t >> 6] = p;
  __syncthreads();
  if (t == 0)
    ((float*)(ws + OFF_PART))[blockIdx.x] = ps[0] + ps[1] + ps[2] + ps[3];
}

// ---------------------------------------------------------------------------
// k4: reduce 16384 partials -> vq_loss = 1.25 * mean((q-x)^2)
// (codebook_loss + 0.25*commitment_loss; both equal numerically)
// ---------------------------------------------------------------------------
__global__ __launch_bounds__(256) void k4_loss(const uint8_t* __restrict__ ws,
                                               float* __restrict__ out,
                                               int out_size) {
  const float* part = (const float*)(ws + OFF_PART);
  float s = 0.0f;
  for (int i = threadIdx.x; i < 16384; i += 256) s += part[i];
  #pragma unroll
  for (int m = 1; m < 64; m <<= 1) s += __shfl_xor(s, m, 64);
  __shared__ float ps[4];
  if ((threadIdx.x & 63) == 0) ps[threadIdx.x >> 6] = s;
  __syncthreads();
  if (threadIdx.x == 0)
    out[out_size - 1] =
        1.25f * (ps[0] + ps[1] + ps[2] + ps[3]) * (1.0f / 16777216.0f);
}

extern "C" void kernel_launch(void* const* d_in, const int* in_sizes, int n_in,
                              void* d_out, int out_size, void* d_ws, size_t ws_size,
                              hipStream_t stream) {
  const float* x = (const float*)d_in[0];        // [65536, 256] fp32
  const float* cb = (const float*)d_in[1];       // [4096, 256] fp32
  uint8_t* ws = (uint8_t*)d_ws;
  float* out = (float*)d_out;                    // 16777216 floats + 1 loss

  k1_prep<<<dim3(NCODES), dim3(64), 0, stream>>>(cb, ws);
  k2_argmin<<<dim3(NROWS / ROWS_WG), dim3(256), 0, stream>>>(x, ws);
  k3_finalize<<<dim3(16384), dim3(256), 0, stream>>>(x, cb, ws, out);
  k4_loss<<<dim3(1), dim3(256), 0, stream>>>(ws, out, out_size);
}

// Round 5
// 267.650 us; speedup vs baseline: 2.9106x; 1.0192x over previous
//
#include <hip/hip_runtime.h>
#include <stdint.h>

// Problem constants (fixed by the reference)
#define DIM     256
#define NCODES  4096
#define NROWS   65536         // 64*32*32
#define ROWS_WG 128
#define CCOLS   64            // codes per chunk in k2
#define NCH     (NCODES / CCOLS)   // 64

// Workspace layout (bytes). Total ~2.33 MB.
#define OFF_BIMG  0u                       // bf16 codebook image: 4096*256*2 = 2 MiB
#define OFF_HC    (1u << 21)               // 4096 floats: 0.125 + 0.5*||e||^2
#define OFF_IDX   ((1u << 21) + 16384u)    // 65536 int best-code indices
#define OFF_PART  (OFF_IDX + 262144u)      // 16384 float per-block loss partials

typedef __attribute__((ext_vector_type(8)))  __bf16 bf16x8;
typedef __attribute__((ext_vector_type(16))) float  f32x16;
typedef const __attribute__((address_space(1))) uint32_t* gas1_t;
typedef __attribute__((address_space(3))) uint32_t*       las3_t;

// fp32 -> bf16 round-to-nearest-even, as a uint16 in the low bits
__device__ __forceinline__ uint32_t f2bf(float f) {
  uint32_t u = __float_as_uint(f);
  return (u + 0x7FFFu + ((u >> 16) & 1u)) >> 16;
}

// ---------------------------------------------------------------------------
// k1: codebook -> bf16 image in MFMA-B layout + hc[] = 0.125 + 0.5*||e||^2
// Image layout per 64-code chunk (32 KiB): byte off = kb*1024 + col*16,
// kb = k/8 (16B of 8 bf16), col = code within chunk. k2's global_load_lds
// staging of a chunk is then a pure linear copy, and B-fragment ds_read_b128
// (32 consecutive cols) is bank-conflict-free.
// ---------------------------------------------------------------------------
__global__ __launch_bounds__(64) void k1_prep(const float* __restrict__ cb,
                                              uint8_t* __restrict__ ws) {
  const int code = blockIdx.x;      // 0..4095
  const int l = threadIdx.x;        // 0..63, handles k = 4l..4l+3
  float4 v = ((const float4*)(cb + (size_t)code * DIM))[l];
  uint32_t lo = f2bf(v.x) | (f2bf(v.y) << 16);
  uint32_t hi = f2bf(v.z) | (f2bf(v.w) << 16);
  uint32_t off = (uint32_t)(code >> 6) * 32768u + (uint32_t)(l >> 1) * 1024u
               + (uint32_t)(code & 63) * 16u + (uint32_t)(l & 1) * 8u;
  uint32_t* dst = (uint32_t*)(ws + OFF_BIMG + off);
  dst[0] = lo;
  dst[1] = hi;
  float s = v.x * v.x + v.y * v.y + v.z * v.z + v.w * v.w;
  #pragma unroll
  for (int m = 1; m < 64; m <<= 1) s += __shfl_xor(s, m, 64);
  if (l == 0) ((float*)(ws + OFF_HC))[code] = 0.125f + 0.5f * s;
}

// ---------------------------------------------------------------------------
// k2: fused bf16-MFMA GEMM + argmin. One WG = 128 rows, loops all 4096 codes.
// A in regs (staged NEGATED: -x), B double-buffered in LDS via global_load_lds.
// acc is initialized to h = 0.125 + 0.5||e||^2 and the MFMA chain accumulates
// -x.e onto it, so the finished accumulator IS the score (no epilogue sub).
// Epilogue per value: v_and_or (embed 12-bit code in low mantissa) + v_min_u32.
// Each WG starts its chunk sweep at a wg-dependent offset (argmin is order-
// independent), de-phasing the two co-resident blocks per CU so one block's
// barrier drain hides under the other's MFMA burst.
// Scores stay positive (0.125 >> |x.e|max) -> fp32 bits order-isomorphic as u32.
// ---------------------------------------------------------------------------
__global__ __launch_bounds__(256, 2) void k2_argmin(const float* __restrict__ x,
                                                    uint8_t* __restrict__ ws) {
  __shared__ uint4 smem4[4096];     // exactly 64 KiB; x2 blocks = 128 <= 160
  char* smem = (char*)&smem4[0];
  const int t = threadIdx.x;
  const int wave = t >> 6;
  const int lane = t & 63;
  const int c = lane & 31;          // MFMA row/col lane index
  const int g = lane >> 5;          // MFMA k-group
  const int wg = blockIdx.x;
  const uint8_t* __restrict__ Bimg = ws + OFF_BIMG;
  const float* __restrict__ hcg = (const float*)(ws + OFF_HC);
  int* bidx = (int*)(ws + OFF_IDX);

  // wave grid: 2x2 over (128 rows x 64 cols); wave tile = 64 rows x 32 cols
  const int rbw = (wave >> 1) * 64;   // wave row base
  const int cbw = (wave & 1) * 32;    // wave col base within chunk

  // ---- stage A tile (128 rows x 256) NEGATED as bf16 across full 64 KiB ----
  // image: byte off = kb*2048 + row*16  (kb = k/8)
  {
    const float* xb = x + (size_t)wg * ROWS_WG * DIM;
    #pragma unroll
    for (int it = 0; it < 16; ++it) {
      int f = it * 256 + t;
      int row = f & 127;
      int kb = f >> 7;              // 0..31
      const float4* src = (const float4*)(xb + (size_t)row * DIM + kb * 8);
      float4 v0 = src[0], v1 = src[1];
      uint4 q;
      q.x = f2bf(-v0.x) | (f2bf(-v0.y) << 16);
      q.y = f2bf(-v0.z) | (f2bf(-v0.w) << 16);
      q.z = f2bf(-v1.x) | (f2bf(-v1.y) << 16);
      q.w = f2bf(-v1.z) | (f2bf(-v1.w) << 16);
      smem4[kb * 128 + row] = q;    // lanes hit consecutive 16B: conflict-free
    }
  }
  __syncthreads();

  // ---- A fragments to registers (mfma_32x32x16 A layout) ----
  bf16x8 a[2][16];
  #pragma unroll
  for (int rt = 0; rt < 2; ++rt)
    #pragma unroll
    for (int ks = 0; ks < 16; ++ks)
      a[rt][ks] = *(const bf16x8*)&smem4[(ks * 2 + g) * 128 + rbw + rt * 32 + c];
  __syncthreads();   // lgkm drained before barrier -> a[] safe; LDS reusable

  auto stageB = [&](int buf, int ch) {
    const uint8_t* gsrc = Bimg + (size_t)ch * 32768 + (size_t)t * 16;
    char* lb = smem + buf * 32768 + (t & 192) * 16;   // wave-uniform base
    #pragma unroll
    for (int i = 0; i < 8; ++i)
      __builtin_amdgcn_global_load_lds((gas1_t)(uintptr_t)(gsrc + i * 4096),
                                       (las3_t)(uintptr_t)(lb + i * 4096),
                                       16, 0, 0);
  };

  uint32_t key[2][16];
  #pragma unroll
  for (int rt = 0; rt < 2; ++rt)
    #pragma unroll
    for (int r = 0; r < 16; ++r) key[rt][r] = 0xFFFFFFFFu;

  const int hoff = cbw + c;
  const uint32_t maskhi = 0xFFFFF000u;     // keep 20 high bits of score

  // de-phase: co-resident blocks (wg, wg+256) start 29 chunks apart
  const int ch0 = ((wg * 7) + ((wg >> 8) * 29)) & 63;

  stageB(0, ch0);
  float h_cur = hcg[ch0 * CCOLS + hoff];

  for (int i = 0; i < NCH; ++i) {
    const int cur = i & 1;
    const int ch = (ch0 + i) & 63;
    const int chn = (ch0 + i + 1) & 63;
    __syncthreads();   // implied vmcnt(0): chunk i landed; prev buf free
    if (i + 1 < NCH) stageB(cur ^ 1, chn);   // async, overlaps compute
    float h_nxt = hcg[chn * CCOLS + hoff];   // prefetch next h

    f32x16 acc0, acc1;
    #pragma unroll
    for (int j = 0; j < 16; ++j) { acc0[j] = h_cur; acc1[j] = h_cur; }
    const int bb = cur * 2048;               // buffer base in uint4 units
    #pragma unroll
    for (int ks = 0; ks < 16; ++ks) {
      bf16x8 b = *(const bf16x8*)&smem4[bb + (ks * 2 + g) * 64 + cbw + c];
      acc0 = __builtin_amdgcn_mfma_f32_32x32x16_bf16(a[0][ks], b, acc0, 0, 0, 0);
      acc1 = __builtin_amdgcn_mfma_f32_32x32x16_bf16(a[1][ks], b, acc1, 0, 0, 0);
    }
    const uint32_t col = (uint32_t)(ch * CCOLS + hoff);
    #pragma unroll
    for (int r = 0; r < 16; ++r) {
      key[0][r] = min(key[0][r], (__float_as_uint(acc0[r]) & maskhi) | col);
      key[1][r] = min(key[1][r], (__float_as_uint(acc1[r]) & maskhi) | col);
    }
    h_cur = h_nxt;
  }

  // ---- cross-lane argmin over the 32 col-lanes (within each 32-lane half) ----
  #pragma unroll
  for (int rt = 0; rt < 2; ++rt)
    #pragma unroll
    for (int r = 0; r < 16; ++r) {
      uint32_t k = key[rt][r];
      #pragma unroll
      for (int m = 1; m < 32; m <<= 1) {
        uint32_t ko = (uint32_t)__shfl_xor((int)k, m, 32);
        k = min(k, ko);
      }
      key[rt][r] = k;
    }

  // ---- combine the two col-waves per row via LDS u32 atomicMin ----
  uint32_t* bk = (uint32_t*)smem;
  __syncthreads();                  // main-loop LDS reads done before reuse
  if (t < 128) bk[t] = 0xFFFFFFFFu;
  __syncthreads();
  if (c == 0) {
    #pragma unroll
    for (int rt = 0; rt < 2; ++rt)
      #pragma unroll
      for (int r = 0; r < 16; ++r) {
        int rl = rbw + rt * 32 + (r & 3) + ((r >> 2) << 3) + (g << 2);
        atomicMin(&bk[rl], key[rt][r]);
      }
  }
  __syncthreads();
  if (t < 128) bidx[wg * ROWS_WG + t] = (int)(bk[t] & 0xFFFu);
}

// ---------------------------------------------------------------------------
// k3: gather fp32 codebook rows -> out0 (== straight-through value to ulp),
// and exact fp32 per-block partial sums of (q - x)^2.
// ---------------------------------------------------------------------------
__global__ __launch_bounds__(256) void k3_finalize(const float* __restrict__ x,
                                                   const float* __restrict__ cb,
                                                   uint8_t* __restrict__ ws,
                                                   float* __restrict__ out) {
  const int t = threadIdx.x;
  const size_t i4 = (size_t)blockIdx.x * 256 + t;   // float4 index
  const int row = (int)(i4 >> 6);
  const int k4 = (int)(i4 & 63);
  const int* bidx = (const int*)(ws + OFF_IDX);
  const int code = bidx[row] & (NCODES - 1);
  float4 q = ((const float4*)(cb + (size_t)code * DIM))[k4];
  float4 xv = ((const float4*)x)[i4];
  ((float4*)out)[i4] = q;
  float dx = q.x - xv.x, dy = q.y - xv.y, dz = q.z - xv.z, dw = q.w - xv.w;
  float p = dx * dx + dy * dy + dz * dz + dw * dw;
  #pragma unroll
  for (int m = 1; m < 64; m <<= 1) p += __shfl_xor(p, m, 64);
  __shared__ float ps[4];
  if ((t & 63) == 0) ps[t >> 6] = p;
  __syncthreads();
  if (t == 0)
    ((float*)(ws + OFF_PART))[blockIdx.x] = ps[0] + ps[1] + ps[2] + ps[3];
}

// ---------------------------------------------------------------------------
// k4: reduce 16384 partials -> vq_loss = 1.25 * mean((q-x)^2)
// (codebook_loss + 0.25*commitment_loss; both equal numerically)
// ---------------------------------------------------------------------------
__global__ __launch_bounds__(256) void k4_loss(const uint8_t* __restrict__ ws,
                                               float* __restrict__ out,
                                               int out_size) {
  const float* part = (const float*)(ws + OFF_PART);
  float s = 0.0f;
  for (int i = threadIdx.x; i < 16384; i += 256) s += part[i];
  #pragma unroll
  for (int m = 1; m < 64; m <<= 1) s += __shfl_xor(s, m, 64);
  __shared__ float ps[4];
  if ((threadIdx.x & 63) == 0) ps[threadIdx.x >> 6] = s;
  __syncthreads();
  if (threadIdx.x == 0)
    out[out_size - 1] =
        1.25f * (ps[0] + ps[1] + ps[2] + ps[3]) * (1.0f / 16777216.0f);
}

extern "C" void kernel_launch(void* const* d_in, const int* in_sizes, int n_in,
                              void* d_out, int out_size, void* d_ws, size_t ws_size,
                              hipStream_t stream) {
  const float* x = (const float*)d_in[0];        // [65536, 256] fp32
  const float* cb = (const float*)d_in[1];       // [4096, 256] fp32
  uint8_t* ws = (uint8_t*)d_ws;
  float* out = (float*)d_out;                    // 16777216 floats + 1 loss

  k1_prep<<<dim3(NCODES), dim3(64), 0, stream>>>(cb, ws);
  k2_argmin<<<dim3(NROWS / ROWS_WG), dim3(256), 0, stream>>>(x, ws);
  k3_finalize<<<dim3(16384), dim3(256), 0, stream>>>(x, cb, ws, out);
  k4_loss<<<dim3(1), dim3(256), 0, stream>>>(ws, out, out_size);
}